// Round 13
// baseline (310.784 us; speedup 1.0000x reference)
//
#include <hip/hip_runtime.h>

typedef __bf16 bf16x8 __attribute__((ext_vector_type(8)));
typedef float  f32x4  __attribute__((ext_vector_type(4)));

#define DEVI static __device__ __forceinline__

// Drain all outstanding LDS ops, then pin program order (rule #18).
#define LDS_FENCE() do { \
  asm volatile("s_waitcnt lgkmcnt(0)" ::: "memory"); \
  __builtin_amdgcn_sched_barrier(0); \
} while (0)

DEVI unsigned short f2bf(float f) {          // native cvt
  __bf16 h = (__bf16)f;
  return __builtin_bit_cast(unsigned short, h);
}
DEVI float bf2f(unsigned short s) {
  union { unsigned u; float f; } v; v.u = ((unsigned)s) << 16;
  return v.f;
}

// ---------------- prep: weights -> bf16, rel-pos bias expand, Wqkv rowsums ----
__global__ void prep_kernel(const float* __restrict__ Wqkv, const float* __restrict__ Wproj,
                            const float* __restrict__ table,
                            unsigned short* __restrict__ wq, unsigned short* __restrict__ wp,
                            float* __restrict__ biasg, float* __restrict__ rowsum) {
  const int i = blockIdx.x * 256 + threadIdx.x;
  if (i < 768 * 256) wq[i] = f2bf(Wqkv[i]);
  if (i < 256 * 256) wp[i] = f2bf(Wproj[i]);
  if (i < 8 * 64 * 64) {
    const int h = i >> 12, r = (i >> 6) & 63, c = i & 63;
    const int ridx = ((r >> 3) - (c >> 3) + 7) * 15 + ((r & 7) - (c & 7) + 7);
    biasg[i] = table[ridx * 8 + h];
  }
  if (i < 768) {
    const float4* p = reinterpret_cast<const float4*>(Wqkv + (size_t)i * 256);
    float s = 0.f;
#pragma unroll
    for (int j = 0; j < 64; ++j) { const float4 a = p[j]; s += a.x + a.y + a.z + a.w; }
    rowsum[i] = s;
  }
}

// LDS (73728 B -> 2 blocks/CU):
//  XN  @ 0     : 64 rows x 512B, xhat bf16 [l][c] XOR-swizzled; alive ph0d->ph5
//  ST4 @ 32768 : 256 x float4 {mean, sigma, rstd, 0} (4096B); alive ph0c->ph5
//  SCR @ 36864 : 36864B. Phase 0b/0c: PART[c][wave] float2 partial sums (16KB).
//                Phase 4: per-wave 4608B slot: vT [32][144B] (kappa-permuted cols),
//                then AO [64][64B] overlay. Phase 5: all waves read AO slots.
#define LDS_XN  0u
#define LDS_ST  32768u
#define LDS_SCR 36864u
#define LDS_TOTAL 73728u

__global__ void __launch_bounds__(512, 2)
win_attn_kernel(const float* __restrict__ X,
                const float* __restrict__ preg, const float* __restrict__ preb,
                const float* __restrict__ postg, const float* __restrict__ postb,
                const float* __restrict__ bqkv, const float* __restrict__ bproj,
                const unsigned short* __restrict__ wq, const unsigned short* __restrict__ wp,
                const float* __restrict__ biasg, const float* __restrict__ rowsum,
                float* __restrict__ out) {
  __shared__ alignas(16) unsigned char sh[LDS_TOTAL];
  const int tid = threadIdx.x;
  const int w = tid >> 6;
  const int lane = tid & 63, lm = lane & 15, lg = lane >> 4;
  const int orig = blockIdx.x;
  const int b = (orig & 7) * 256 + (orig >> 3);
  const int n = b >> 8, gh = (b >> 4) & 15, gw = b & 15;
  const size_t wbase = (size_t)n * 4194304 + (size_t)gh * 1024 + (size_t)gw * 8;

  // ---------- phase 0: coalesced load; thread (l = tid>>3, w0 = tid&7) holds
  // channels c = w0*32 + w1*4 + i at location l, all in registers ----------
  const int l0 = tid >> 3, w0 = tid & 7;
  float fv[4][8];
#pragma unroll
  for (int i = 0; i < 4; ++i) {
    const int cc = i * 64 + l0;
    const float* xb = X + wbase + (size_t)cc * 16384 + w0 * 128;
    const float4 a  = *reinterpret_cast<const float4*>(xb);
    const float4 bv = *reinterpret_cast<const float4*>(xb + 4);
    fv[i][0] = a.x;  fv[i][1] = a.y;  fv[i][2] = a.z;  fv[i][3] = a.w;
    fv[i][4] = bv.x; fv[i][5] = bv.y; fv[i][6] = bv.z; fv[i][7] = bv.w;
  }
  // ---------- phase 0b: per-wave channel partials via shfl; lanes 0-7 write ---
#pragma unroll
  for (int i = 0; i < 4; ++i)
#pragma unroll
    for (int j = 0; j < 8; ++j) {
      float s = fv[i][j];
      float q = s * s;
      s += __shfl_xor(s, 8);  q += __shfl_xor(q, 8);
      s += __shfl_xor(s, 16); q += __shfl_xor(q, 16);
      s += __shfl_xor(s, 32); q += __shfl_xor(q, 32);
      if (lane < 8) {
        const int c = lane * 32 + j * 4 + i;
        *reinterpret_cast<float2*>(sh + LDS_SCR + (unsigned)(c * 64 + w * 8)) = float2{s, q};
      }
    }
  __syncthreads();

  // ---------- phase 0c: reduce 8 wave-partials per channel -> ST4 -------------
  if (tid < 256) {
    const int c = tid;
    const float4 p0 = *reinterpret_cast<const float4*>(sh + LDS_SCR + (unsigned)(c * 64));
    const float4 p1 = *reinterpret_cast<const float4*>(sh + LDS_SCR + (unsigned)(c * 64 + 16));
    const float4 p2 = *reinterpret_cast<const float4*>(sh + LDS_SCR + (unsigned)(c * 64 + 32));
    const float4 p3 = *reinterpret_cast<const float4*>(sh + LDS_SCR + (unsigned)(c * 64 + 48));
    const float s1 = p0.x + p0.z + p1.x + p1.z + p2.x + p2.z + p3.x + p3.z;
    const float s2 = p0.y + p0.w + p1.y + p1.w + p2.y + p2.w + p3.y + p3.w;
    const float mean = s1 * (1.f / 64.f);
    float var = fmaxf(s2 * (1.f / 64.f) - mean * mean, 0.f) + 1e-5f;
    const float rstd = rsqrtf(var);
    const float sig  = var * rstd;      // sqrt(var+eps)
    *reinterpret_cast<float4*>(sh + LDS_ST + (unsigned)(c * 16)) = float4{mean, sig, rstd, 0.f};
  }
  __syncthreads();

  // ---------- phase 0d: normalize register-held values -> bf16 XN [l][c] ------
#pragma unroll
  for (int i = 0; i < 4; ++i)
#pragma unroll
    for (int j = 0; j < 8; ++j) {
      const int c = w0 * 32 + j * 4 + i;
      const float4 st = *reinterpret_cast<const float4*>(sh + LDS_ST + (unsigned)(c * 16));
      *(unsigned short*)(sh + LDS_XN + l0 * 512 +
          (((unsigned)(2 * c)) ^ ((unsigned)((l0 & 7) << 4)))) = f2bf((fv[i][j] - st.x) * st.z);
    }
  // prefetch QKV A-fragments for head w (hidden under the barrier)
  const unsigned char* wqb = (const unsigned char*)wq;
  size_t aoff[6];
  bf16x8 acur[6];
#pragma unroll
  for (int t = 0; t < 6; ++t) {
    const int o = (t >> 1) * 256 + 32 * w + 16 * (t & 1) + lm;   // q/k/v of head w
    aoff[t] = (size_t)o * 512 + lg * 16;
    acur[t] = *reinterpret_cast<const bf16x8*>(wqb + aoff[t]);
  }
  __syncthreads();

  // ---------- phase 2 (R12 verbatim): QKV GEMM, wave w -> head w's q,k,v ------
  float pg4[4], pb4[4];
#pragma unroll
  for (int nt = 0; nt < 4; ++nt) { pg4[nt] = preg[nt * 16 + lm]; pb4[nt] = preb[nt * 16 + lm]; }
  f32x4 acc6[6][4];
#pragma unroll
  for (int t = 0; t < 6; ++t)
#pragma unroll
    for (int j = 0; j < 4; ++j) acc6[t][j] = f32x4{0.f, 0.f, 0.f, 0.f};
#pragma unroll
  for (int ks = 0; ks < 8; ++ks) {
    bf16x8 anxt[6];
    if (ks < 7) {
#pragma unroll
      for (int t = 0; t < 6; ++t)
        anxt[t] = *reinterpret_cast<const bf16x8*>(wqb + aoff[t] + (ks + 1) * 64);
    }
    bf16x8 bfrag[4];
#pragma unroll
    for (int nt = 0; nt < 4; ++nt) {
      const int l = nt * 16 + lm;
      bfrag[nt] = *reinterpret_cast<const bf16x8*>(
          sh + LDS_XN + l * 512 + (((unsigned)(ks * 64 + lg * 16)) ^ ((unsigned)((l & 7) << 4))));
    }
#pragma unroll
    for (int t = 0; t < 6; ++t)
#pragma unroll
      for (int nt = 0; nt < 4; ++nt)
        acc6[t][nt] = __builtin_amdgcn_mfma_f32_16x16x32_bf16(acur[t], bfrag[nt], acc6[t][nt], 0, 0, 0);
    if (ks < 7) {
#pragma unroll
      for (int t = 0; t < 6; ++t) acur[t] = anxt[t];
    }
  }
  // affine + bias fold
#pragma unroll
  for (int t = 0; t < 6; ++t) {
    const int ob = (t >> 1) * 256 + 32 * w + 16 * (t & 1);
    const f32x4 rs4 = *reinterpret_cast<const f32x4*>(rowsum + ob + lg * 4);
    const f32x4 bq4 = *reinterpret_cast<const f32x4*>(bqkv   + ob + lg * 4);
#pragma unroll
    for (int nt = 0; nt < 4; ++nt)
#pragma unroll
      for (int reg = 0; reg < 4; ++reg)
        acc6[t][nt][reg] = pg4[nt] * acc6[t][nt][reg] + pb4[nt] * rs4[reg] + bq4[reg];
  }
  // folded L2-norm over d for q (t=0,1) and k (t=2,3)
#pragma unroll
  for (int sec = 0; sec < 2; ++sec)
#pragma unroll
    for (int nt = 0; nt < 4; ++nt) {
      float ss = 0.f;
#pragma unroll
      for (int sub = 0; sub < 2; ++sub)
#pragma unroll
        for (int reg = 0; reg < 4; ++reg) {
          const float v = acc6[2 * sec + sub][nt][reg];
          ss += v * v;
        }
      ss += __shfl_xor(ss, 16);
      ss += __shfl_xor(ss, 32);
      const float inv = 1.f / fmaxf(sqrtf(ss), 1e-12f);
#pragma unroll
      for (int sub = 0; sub < 2; ++sub)
#pragma unroll
        for (int reg = 0; reg < 4; ++reg)
          acc6[2 * sec + sub][nt][reg] *= inv;
    }

  // ---------- phase 4 (R12 verbatim): wave-local attention (S^T, P in regs) ---
  const unsigned scr = LDS_SCR + (unsigned)w * 4608u;
  // q/k fragments in-register: shared slot->d bijection kappa(lg,i)=16*(i>>2)+4lg+(i&3)
  bf16x8 qfrag[4], kfrag[4];
#pragma unroll
  for (int nt = 0; nt < 4; ++nt) {
    bf16x8 qv, kv;
#pragma unroll
    for (int sub = 0; sub < 2; ++sub)
#pragma unroll
      for (int reg = 0; reg < 4; ++reg) {
        qv[sub * 4 + reg] = (__bf16)acc6[sub][nt][reg];
        kv[sub * 4 + reg] = (__bf16)acc6[2 + sub][nt][reg];
      }
    qfrag[nt] = qv; kfrag[nt] = kv;
  }
  // vT -> own SCR [d][144B], columns permuted so ds_read slots match kappa above:
  // value v[d][m=nt*16+lm] stored at col p = (nt>>1)*32 + (lm>>2)*8 + (nt&1)*4 + (lm&3)
#pragma unroll
  for (int sub = 0; sub < 2; ++sub)
#pragma unroll
    for (int reg = 0; reg < 4; ++reg) {
      const int d = 16 * sub + 4 * lg + reg;
#pragma unroll
      for (int nt = 0; nt < 4; ++nt) {
        const int pcol = (nt >> 1) * 32 + (lm >> 2) * 8 + (nt & 1) * 4 + (lm & 3);
        *(unsigned short*)(sh + scr + (unsigned)(d * 144 + 2 * pcol)) =
            f2bf(acc6[4 + sub][nt][reg]);
      }
    }
  LDS_FENCE();                                     // RAW: vT writes -> vf reads
  bf16x8 vf[2][2];
#pragma unroll
  for (int ks = 0; ks < 2; ++ks)
#pragma unroll
    for (int mtd = 0; mtd < 2; ++mtd)
      vf[ks][mtd] = *reinterpret_cast<const bf16x8*>(
          sh + scr + (unsigned)((mtd * 16 + lm) * 144 + ks * 64 + lg * 16));
  LDS_FENCE();                                     // WAR: vf reads -> AO writes later

  const float* bh = biasg + w * 4096;              // bias[h][l][m]
  f32x4 oaccT[2][4];
#pragma unroll
  for (int mtd = 0; mtd < 2; ++mtd)
#pragma unroll
    for (int nt = 0; nt < 4; ++nt) oaccT[mtd][nt] = f32x4{0.f, 0.f, 0.f, 0.f};
#pragma unroll
  for (int nt = 0; nt < 4; ++nt) {
    // bias for columns l = nt*16+lm, rows m = mt*16+4lg+reg (f32x4 over reg)
    f32x4 bb[4];
#pragma unroll
    for (int mt = 0; mt < 4; ++mt)
      bb[mt] = *reinterpret_cast<const f32x4*>(bh + (nt * 16 + lm) * 64 + mt * 16 + 4 * lg);
    // S^T tile column-block nt: rows m via (mt,lg,reg), col l via lm
    f32x4 st[4];
#pragma unroll
    for (int mt = 0; mt < 4; ++mt)
      st[mt] = __builtin_amdgcn_mfma_f32_16x16x32_bf16(kfrag[mt], qfrag[nt],
                                                       f32x4{0.f,0.f,0.f,0.f}, 0, 0, 0);
    // softmax over m: 16 in-lane + lg cross-lane (shfl 16,32)
    float mmax = -1e30f;
#pragma unroll
    for (int mt = 0; mt < 4; ++mt)
#pragma unroll
      for (int reg = 0; reg < 4; ++reg) {
        st[mt][reg] += bb[mt][reg];
        mmax = fmaxf(mmax, st[mt][reg]);
      }
    mmax = fmaxf(mmax, __shfl_xor(mmax, 16));
    mmax = fmaxf(mmax, __shfl_xor(mmax, 32));
    float sum = 0.f;
#pragma unroll
    for (int mt = 0; mt < 4; ++mt)
#pragma unroll
      for (int reg = 0; reg < 4; ++reg) {
        const float e = __expf(st[mt][reg] - mmax);
        st[mt][reg] = e;
        sum += e;
      }
    sum += __shfl_xor(sum, 16);
    sum += __shfl_xor(sum, 32);
    const float rinv = 1.f / sum;
    // PV: pf slot i=4sub+reg <- P[m=ks*32+16sub+4lg+reg][l]*rinv (matches vf's kappa)
#pragma unroll
    for (int ks = 0; ks < 2; ++ks) {
      bf16x8 pf;
#pragma unroll
      for (int sub = 0; sub < 2; ++sub)
#pragma unroll
        for (int reg = 0; reg < 4; ++reg)
          pf[sub * 4 + reg] = (__bf16)(st[2 * ks + sub][reg] * rinv);
#pragma unroll
      for (int mtd = 0; mtd < 2; ++mtd)
        oaccT[mtd][nt] = __builtin_amdgcn_mfma_f32_16x16x32_bf16(vf[ks][mtd], pf,
                                                                 oaccT[mtd][nt], 0, 0, 0);
    }
  }
  // AO -> own SCR [l][64B] rows (true-d columns; overwrites vT, vf long consumed)
#pragma unroll
  for (int mtd = 0; mtd < 2; ++mtd)
#pragma unroll
    for (int reg = 0; reg < 4; ++reg) {
      const int d = mtd * 16 + 4 * lg + reg;
#pragma unroll
      for (int nt = 0; nt < 4; ++nt)
        *(unsigned short*)(sh + scr + (unsigned)((nt * 16 + lm) * 64 + 2 * d)) =
            f2bf(oaccT[mtd][nt][reg]);
    }

  // prefetch proj A (global; hidden under the barrier)
  const unsigned char* wpb = (const unsigned char*)wp;
  size_t poff[2];
  bf16x8 pcur[2];
#pragma unroll
  for (int mt = 0; mt < 2; ++mt) {
    poff[mt] = (size_t)(w * 32 + mt * 16 + lm) * 512 + lg * 16;
    pcur[mt] = *reinterpret_cast<const bf16x8*>(wpb + poff[mt]);
  }
  __syncthreads();   // all AO slots visible block-wide

  // ---------- phase 5 (R12 verbatim, ST stride 16): proj + residual + post-LN --
  {
    float pog4[4], pob4[4];
#pragma unroll
    for (int nt = 0; nt < 4; ++nt) { pog4[nt] = postg[nt * 16 + lm]; pob4[nt] = postb[nt * 16 + lm]; }
    f32x4 pacc[2][4];
#pragma unroll
    for (int i = 0; i < 2; ++i)
#pragma unroll
      for (int j = 0; j < 4; ++j) pacc[i][j] = f32x4{0.f, 0.f, 0.f, 0.f};
#pragma unroll
    for (int ks = 0; ks < 8; ++ks) {
      bf16x8 pnxt[2];
      if (ks < 7) {
#pragma unroll
        for (int mt = 0; mt < 2; ++mt)
          pnxt[mt] = *reinterpret_cast<const bf16x8*>(wpb + poff[mt] + (ks + 1) * 64);
      }
      bf16x8 bfr[4];
#pragma unroll
      for (int nt = 0; nt < 4; ++nt)
        bfr[nt] = *reinterpret_cast<const bf16x8*>(
            sh + LDS_SCR + (unsigned)(ks * 4608 + (nt * 16 + lm) * 64 + lg * 16));
#pragma unroll
      for (int mt = 0; mt < 2; ++mt)
#pragma unroll
        for (int nt = 0; nt < 4; ++nt)
          pacc[mt][nt] = __builtin_amdgcn_mfma_f32_16x16x32_bf16(pcur[mt], bfr[nt], pacc[mt][nt], 0, 0, 0);
      if (ks < 7) {
#pragma unroll
        for (int mt = 0; mt < 2; ++mt) pcur[mt] = pnxt[mt];
      }
    }
#pragma unroll
    for (int mt = 0; mt < 2; ++mt) {
      const float4 bp4 = *reinterpret_cast<const float4*>(bproj + w * 32 + mt * 16 + lg * 4);
#pragma unroll
      for (int reg = 0; reg < 4; ++reg) {
        const int c = w * 32 + mt * 16 + lg * 4 + reg;
        const float bp = ((const float*)&bp4)[reg];
        const float4 ms4 = *reinterpret_cast<const float4*>(sh + LDS_ST + (unsigned)(c * 16));
        float y[4];
        float s1 = 0.f, s2 = 0.f;
#pragma unroll
        for (int nt = 0; nt < 4; ++nt) {
          const int l = nt * 16 + lm;
          const float xh = bf2f(*(const unsigned short*)(
              sh + LDS_XN + l * 512 + (((unsigned)(2 * c)) ^ ((unsigned)((l & 7) << 4)))));
          const float v = xh * ms4.y + ms4.x + pacc[mt][nt][reg] + bp;
          y[nt] = v;
          s1 += v; s2 += v * v;
        }
        s1 += __shfl_xor(s1, 1); s2 += __shfl_xor(s2, 1);
        s1 += __shfl_xor(s1, 2); s2 += __shfl_xor(s2, 2);
        s1 += __shfl_xor(s1, 4); s2 += __shfl_xor(s2, 4);
        s1 += __shfl_xor(s1, 8); s2 += __shfl_xor(s2, 8);
        const float mean = s1 * (1.f / 64.f);
        const float var  = s2 * (1.f / 64.f) - mean * mean;
        const float rstd = rsqrtf(fmaxf(var, 0.f) + 1e-5f);
        float* orow = out + (size_t)b * 16384 + (size_t)c * 64;
#pragma unroll
        for (int nt = 0; nt < 4; ++nt) {
          const float v = y[nt];
          orow[nt * 16 + lm] = v + (v - mean) * rstd * pog4[nt] + pob4[nt];
        }
      }
    }
  }
}

extern "C" void kernel_launch(void* const* d_in, const int* in_sizes, int n_in,
                              void* d_out, int out_size, void* d_ws, size_t ws_size,
                              hipStream_t stream) {
  const float* X     = (const float*)d_in[0];
  const float* preg  = (const float*)d_in[1];
  const float* preb  = (const float*)d_in[2];
  const float* postg = (const float*)d_in[3];
  const float* postb = (const float*)d_in[4];
  const float* Wqkv  = (const float*)d_in[5];
  const float* bqkv  = (const float*)d_in[6];
  const float* Wproj = (const float*)d_in[7];
  const float* bproj = (const float*)d_in[8];
  const float* table = (const float*)d_in[9];

  unsigned short* wq = (unsigned short*)d_ws;                    // 768*256 bf16
  unsigned short* wp = (unsigned short*)((char*)d_ws + 393216);  // 256*256 bf16
  float* biasg       = (float*)((char*)d_ws + 524288);           // 8*64*64 f32
  float* rowsum      = (float*)((char*)d_ws + 655360);           // 768 f32

  prep_kernel<<<768, 256, 0, stream>>>(Wqkv, Wproj, table, wq, wp, biasg, rowsum);
  win_attn_kernel<<<2048, 512, 0, stream>>>(X, preg, preb, postg, postb,
                                            bqkv, bproj, wq, wp, biasg, rowsum,
                                            (float*)d_out);
}

// Round 14
// 267.538 us; speedup vs baseline: 1.1616x; 1.1616x over previous
//
#include <hip/hip_runtime.h>

typedef __bf16 bf16x8 __attribute__((ext_vector_type(8)));
typedef float  f32x4  __attribute__((ext_vector_type(4)));

#define DEVI static __device__ __forceinline__

// Drain all outstanding LDS ops, then pin program order (rule #18).
#define LDS_FENCE() do { \
  asm volatile("s_waitcnt lgkmcnt(0)" ::: "memory"); \
  __builtin_amdgcn_sched_barrier(0); \
} while (0)

DEVI unsigned short f2bf(float f) {          // native cvt
  __bf16 h = (__bf16)f;
  return __builtin_bit_cast(unsigned short, h);
}
DEVI float bf2f(unsigned short s) {
  union { unsigned u; float f; } v; v.u = ((unsigned)s) << 16;
  return v.f;
}

// ---------------- prep: weights -> bf16, rel-pos bias expand, Wqkv rowsums ----
__global__ void prep_kernel(const float* __restrict__ Wqkv, const float* __restrict__ Wproj,
                            const float* __restrict__ table,
                            unsigned short* __restrict__ wq, unsigned short* __restrict__ wp,
                            float* __restrict__ biasg, float* __restrict__ rowsum) {
  const int i = blockIdx.x * 256 + threadIdx.x;
  if (i < 768 * 256) wq[i] = f2bf(Wqkv[i]);
  if (i < 256 * 256) wp[i] = f2bf(Wproj[i]);
  if (i < 8 * 64 * 64) {
    const int h = i >> 12, r = (i >> 6) & 63, c = i & 63;
    const int ridx = ((r >> 3) - (c >> 3) + 7) * 15 + ((r & 7) - (c & 7) + 7);
    biasg[i] = table[ridx * 8 + h];
  }
  if (i < 768) {
    const float4* p = reinterpret_cast<const float4*>(Wqkv + (size_t)i * 256);
    float s = 0.f;
#pragma unroll
    for (int j = 0; j < 64; ++j) { const float4 a = p[j]; s += a.x + a.y + a.z + a.w; }
    rowsum[i] = s;
  }
}

// LDS (73728 B -> 2 blocks/CU):
//  XN  @ 0     : 64 rows x 512B, xhat bf16 [l][c] XOR-swizzled; alive ph1->ph5
//  ST4 @ 32768 : 256 x float4 {mean, sigma, rstd, 0} (4096B); alive ph1->ph5
//  SCR @ 36864 : 36864B. Phase 4: per-wave 4608B slot: vT [32][144B] (kappa-permuted
//                cols), then AO [64][64B] overlay. Phase 5: all waves read AO slots.
//                (Untouched before phase 4 — phase 0/1 uses no scratch at all.)
#define LDS_XN  0u
#define LDS_ST  32768u
#define LDS_SCR 36864u
#define LDS_TOTAL 73728u

__global__ void __launch_bounds__(512, 2)
win_attn_kernel(const float* __restrict__ X,
                const float* __restrict__ preg, const float* __restrict__ preb,
                const float* __restrict__ postg, const float* __restrict__ postb,
                const float* __restrict__ bqkv, const float* __restrict__ bproj,
                const unsigned short* __restrict__ wq, const unsigned short* __restrict__ wp,
                const float* __restrict__ biasg, const float* __restrict__ rowsum,
                float* __restrict__ out) {
  __shared__ alignas(16) unsigned char sh[LDS_TOTAL];
  const int tid = threadIdx.x;
  const int w = tid >> 6;
  const int lane = tid & 63, lm = lane & 15, lg = lane >> 4;
  const int orig = blockIdx.x;
  const int b = (orig & 7) * 256 + (orig >> 3);
  const int n = b >> 8, gh = (b >> 4) & 15, gw = b & 15;
  const size_t wbase = (size_t)n * 4194304 + (size_t)gh * 1024 + (size_t)gw * 8;

  // ---------- phase 0/1 fused: LN straight from global (no staging arena) -----
  // xp[c][l] = X[n][(c&3)*64+l][gh*8 + (c>>5)][gw*8 + ((c>>2)&7)]
  // thread (c = tid>>1, half = tid&1) reads its 32 l-values as scalar f32 loads.
  {
    const int c = tid >> 1, half = tid & 1;
    const float* xb = X + wbase
                    + ((size_t)((c & 3) * 64 + half * 32)) * 16384
                    + (c >> 5) * 128 + ((c >> 2) & 7);
    float fv[32];
    float s1 = 0.f, s2 = 0.f;
#pragma unroll
    for (int i = 0; i < 32; ++i) {
      const float v = xb[(size_t)i * 16384];
      fv[i] = v; s1 += v; s2 += v * v;
    }
    s1 += __shfl_xor(s1, 1);
    s2 += __shfl_xor(s2, 1);
    const float mean = s1 * (1.f / 64.f);
    float var = fmaxf(s2 * (1.f / 64.f) - mean * mean, 0.f) + 1e-5f;
    const float rstd = rsqrtf(var);
    const float sig  = var * rstd;      // sqrt(var+eps)
    const unsigned colb = (unsigned)(2 * c);
#pragma unroll
    for (int i = 0; i < 32; ++i) {
      const int l = half * 32 + i;
      *(unsigned short*)(sh + LDS_XN + l * 512 +
          (colb ^ ((unsigned)((l & 7) << 4)))) = f2bf((fv[i] - mean) * rstd);
    }
    if (!half)
      *reinterpret_cast<float4*>(sh + LDS_ST + (unsigned)(c * 16)) = float4{mean, sig, rstd, 0.f};
  }
  // prefetch QKV A-fragments for head w (hidden under the barrier)
  const unsigned char* wqb = (const unsigned char*)wq;
  size_t aoff[6];
  bf16x8 acur[6];
#pragma unroll
  for (int t = 0; t < 6; ++t) {
    const int o = (t >> 1) * 256 + 32 * w + 16 * (t & 1) + lm;   // q/k/v of head w
    aoff[t] = (size_t)o * 512 + lg * 16;
    acur[t] = *reinterpret_cast<const bf16x8*>(wqb + aoff[t]);
  }
  __syncthreads();

  // ---------- phase 2 (R12/R13 verbatim): QKV GEMM, wave w -> head w's q,k,v --
  float pg4[4], pb4[4];
#pragma unroll
  for (int nt = 0; nt < 4; ++nt) { pg4[nt] = preg[nt * 16 + lm]; pb4[nt] = preb[nt * 16 + lm]; }
  f32x4 acc6[6][4];
#pragma unroll
  for (int t = 0; t < 6; ++t)
#pragma unroll
    for (int j = 0; j < 4; ++j) acc6[t][j] = f32x4{0.f, 0.f, 0.f, 0.f};
#pragma unroll
  for (int ks = 0; ks < 8; ++ks) {
    bf16x8 anxt[6];
    if (ks < 7) {
#pragma unroll
      for (int t = 0; t < 6; ++t)
        anxt[t] = *reinterpret_cast<const bf16x8*>(wqb + aoff[t] + (ks + 1) * 64);
    }
    bf16x8 bfrag[4];
#pragma unroll
    for (int nt = 0; nt < 4; ++nt) {
      const int l = nt * 16 + lm;
      bfrag[nt] = *reinterpret_cast<const bf16x8*>(
          sh + LDS_XN + l * 512 + (((unsigned)(ks * 64 + lg * 16)) ^ ((unsigned)((l & 7) << 4))));
    }
#pragma unroll
    for (int t = 0; t < 6; ++t)
#pragma unroll
      for (int nt = 0; nt < 4; ++nt)
        acc6[t][nt] = __builtin_amdgcn_mfma_f32_16x16x32_bf16(acur[t], bfrag[nt], acc6[t][nt], 0, 0, 0);
    if (ks < 7) {
#pragma unroll
      for (int t = 0; t < 6; ++t) acur[t] = anxt[t];
    }
  }
  // affine + bias fold
#pragma unroll
  for (int t = 0; t < 6; ++t) {
    const int ob = (t >> 1) * 256 + 32 * w + 16 * (t & 1);
    const f32x4 rs4 = *reinterpret_cast<const f32x4*>(rowsum + ob + lg * 4);
    const f32x4 bq4 = *reinterpret_cast<const f32x4*>(bqkv   + ob + lg * 4);
#pragma unroll
    for (int nt = 0; nt < 4; ++nt)
#pragma unroll
      for (int reg = 0; reg < 4; ++reg)
        acc6[t][nt][reg] = pg4[nt] * acc6[t][nt][reg] + pb4[nt] * rs4[reg] + bq4[reg];
  }
  // folded L2-norm over d for q (t=0,1) and k (t=2,3)
#pragma unroll
  for (int sec = 0; sec < 2; ++sec)
#pragma unroll
    for (int nt = 0; nt < 4; ++nt) {
      float ss = 0.f;
#pragma unroll
      for (int sub = 0; sub < 2; ++sub)
#pragma unroll
        for (int reg = 0; reg < 4; ++reg) {
          const float v = acc6[2 * sec + sub][nt][reg];
          ss += v * v;
        }
      ss += __shfl_xor(ss, 16);
      ss += __shfl_xor(ss, 32);
      const float inv = 1.f / fmaxf(sqrtf(ss), 1e-12f);
#pragma unroll
      for (int sub = 0; sub < 2; ++sub)
#pragma unroll
        for (int reg = 0; reg < 4; ++reg)
          acc6[2 * sec + sub][nt][reg] *= inv;
    }

  // ---------- phase 4 (R12/R13 verbatim): wave-local attention (S^T, P in regs)
  const unsigned scr = LDS_SCR + (unsigned)w * 4608u;
  // q/k fragments in-register: shared slot->d bijection kappa(lg,i)=16*(i>>2)+4lg+(i&3)
  bf16x8 qfrag[4], kfrag[4];
#pragma unroll
  for (int nt = 0; nt < 4; ++nt) {
    bf16x8 qv, kv;
#pragma unroll
    for (int sub = 0; sub < 2; ++sub)
#pragma unroll
      for (int reg = 0; reg < 4; ++reg) {
        qv[sub * 4 + reg] = (__bf16)acc6[sub][nt][reg];
        kv[sub * 4 + reg] = (__bf16)acc6[2 + sub][nt][reg];
      }
    qfrag[nt] = qv; kfrag[nt] = kv;
  }
  // vT -> own SCR [d][144B], columns permuted so ds_read slots match kappa above:
  // value v[d][m=nt*16+lm] stored at col p = (nt>>1)*32 + (lm>>2)*8 + (nt&1)*4 + (lm&3)
#pragma unroll
  for (int sub = 0; sub < 2; ++sub)
#pragma unroll
    for (int reg = 0; reg < 4; ++reg) {
      const int d = 16 * sub + 4 * lg + reg;
#pragma unroll
      for (int nt = 0; nt < 4; ++nt) {
        const int pcol = (nt >> 1) * 32 + (lm >> 2) * 8 + (nt & 1) * 4 + (lm & 3);
        *(unsigned short*)(sh + scr + (unsigned)(d * 144 + 2 * pcol)) =
            f2bf(acc6[4 + sub][nt][reg]);
      }
    }
  LDS_FENCE();                                     // RAW: vT writes -> vf reads
  bf16x8 vf[2][2];
#pragma unroll
  for (int ks = 0; ks < 2; ++ks)
#pragma unroll
    for (int mtd = 0; mtd < 2; ++mtd)
      vf[ks][mtd] = *reinterpret_cast<const bf16x8*>(
          sh + scr + (unsigned)((mtd * 16 + lm) * 144 + ks * 64 + lg * 16));
  LDS_FENCE();                                     // WAR: vf reads -> AO writes later

  const float* bh = biasg + w * 4096;              // bias[h][l][m]
  f32x4 oaccT[2][4];
#pragma unroll
  for (int mtd = 0; mtd < 2; ++mtd)
#pragma unroll
    for (int nt = 0; nt < 4; ++nt) oaccT[mtd][nt] = f32x4{0.f, 0.f, 0.f, 0.f};
#pragma unroll
  for (int nt = 0; nt < 4; ++nt) {
    // bias for columns l = nt*16+lm, rows m = mt*16+4lg+reg (f32x4 over reg)
    f32x4 bb[4];
#pragma unroll
    for (int mt = 0; mt < 4; ++mt)
      bb[mt] = *reinterpret_cast<const f32x4*>(bh + (nt * 16 + lm) * 64 + mt * 16 + 4 * lg);
    // S^T tile column-block nt: rows m via (mt,lg,reg), col l via lm
    f32x4 st[4];
#pragma unroll
    for (int mt = 0; mt < 4; ++mt)
      st[mt] = __builtin_amdgcn_mfma_f32_16x16x32_bf16(kfrag[mt], qfrag[nt],
                                                       f32x4{0.f,0.f,0.f,0.f}, 0, 0, 0);
    // softmax over m: 16 in-lane + lg cross-lane (shfl 16,32)
    float mmax = -1e30f;
#pragma unroll
    for (int mt = 0; mt < 4; ++mt)
#pragma unroll
      for (int reg = 0; reg < 4; ++reg) {
        st[mt][reg] += bb[mt][reg];
        mmax = fmaxf(mmax, st[mt][reg]);
      }
    mmax = fmaxf(mmax, __shfl_xor(mmax, 16));
    mmax = fmaxf(mmax, __shfl_xor(mmax, 32));
    float sum = 0.f;
#pragma unroll
    for (int mt = 0; mt < 4; ++mt)
#pragma unroll
      for (int reg = 0; reg < 4; ++reg) {
        const float e = __expf(st[mt][reg] - mmax);
        st[mt][reg] = e;
        sum += e;
      }
    sum += __shfl_xor(sum, 16);
    sum += __shfl_xor(sum, 32);
    const float rinv = 1.f / sum;
    // PV: pf slot i=4sub+reg <- P[m=ks*32+16sub+4lg+reg][l]*rinv (matches vf's kappa)
#pragma unroll
    for (int ks = 0; ks < 2; ++ks) {
      bf16x8 pf;
#pragma unroll
      for (int sub = 0; sub < 2; ++sub)
#pragma unroll
        for (int reg = 0; reg < 4; ++reg)
          pf[sub * 4 + reg] = (__bf16)(st[2 * ks + sub][reg] * rinv);
#pragma unroll
      for (int mtd = 0; mtd < 2; ++mtd)
        oaccT[mtd][nt] = __builtin_amdgcn_mfma_f32_16x16x32_bf16(vf[ks][mtd], pf,
                                                                 oaccT[mtd][nt], 0, 0, 0);
    }
  }
  // AO -> own SCR [l][64B] rows (true-d columns; overwrites vT, vf long consumed)
#pragma unroll
  for (int mtd = 0; mtd < 2; ++mtd)
#pragma unroll
    for (int reg = 0; reg < 4; ++reg) {
      const int d = mtd * 16 + 4 * lg + reg;
#pragma unroll
      for (int nt = 0; nt < 4; ++nt)
        *(unsigned short*)(sh + scr + (unsigned)((nt * 16 + lm) * 64 + 2 * d)) =
            f2bf(oaccT[mtd][nt][reg]);
    }

  // prefetch proj A (global; hidden under the barrier)
  const unsigned char* wpb = (const unsigned char*)wp;
  size_t poff[2];
  bf16x8 pcur[2];
#pragma unroll
  for (int mt = 0; mt < 2; ++mt) {
    poff[mt] = (size_t)(w * 32 + mt * 16 + lm) * 512 + lg * 16;
    pcur[mt] = *reinterpret_cast<const bf16x8*>(wpb + poff[mt]);
  }
  __syncthreads();   // all AO slots visible block-wide

  // ---------- phase 5 (R13 verbatim): proj GEMM + residual + post-LN + store --
  {
    float pog4[4], pob4[4];
#pragma unroll
    for (int nt = 0; nt < 4; ++nt) { pog4[nt] = postg[nt * 16 + lm]; pob4[nt] = postb[nt * 16 + lm]; }
    f32x4 pacc[2][4];
#pragma unroll
    for (int i = 0; i < 2; ++i)
#pragma unroll
      for (int j = 0; j < 4; ++j) pacc[i][j] = f32x4{0.f, 0.f, 0.f, 0.f};
#pragma unroll
    for (int ks = 0; ks < 8; ++ks) {
      bf16x8 pnxt[2];
      if (ks < 7) {
#pragma unroll
        for (int mt = 0; mt < 2; ++mt)
          pnxt[mt] = *reinterpret_cast<const bf16x8*>(wpb + poff[mt] + (ks + 1) * 64);
      }
      bf16x8 bfr[4];
#pragma unroll
      for (int nt = 0; nt < 4; ++nt)
        bfr[nt] = *reinterpret_cast<const bf16x8*>(
            sh + LDS_SCR + (unsigned)(ks * 4608 + (nt * 16 + lm) * 64 + lg * 16));
#pragma unroll
      for (int mt = 0; mt < 2; ++mt)
#pragma unroll
        for (int nt = 0; nt < 4; ++nt)
          pacc[mt][nt] = __builtin_amdgcn_mfma_f32_16x16x32_bf16(pcur[mt], bfr[nt], pacc[mt][nt], 0, 0, 0);
      if (ks < 7) {
#pragma unroll
        for (int mt = 0; mt < 2; ++mt) pcur[mt] = pnxt[mt];
      }
    }
#pragma unroll
    for (int mt = 0; mt < 2; ++mt) {
      const float4 bp4 = *reinterpret_cast<const float4*>(bproj + w * 32 + mt * 16 + lg * 4);
#pragma unroll
      for (int reg = 0; reg < 4; ++reg) {
        const int c = w * 32 + mt * 16 + lg * 4 + reg;
        const float bp = ((const float*)&bp4)[reg];
        const float4 ms4 = *reinterpret_cast<const float4*>(sh + LDS_ST + (unsigned)(c * 16));
        float y[4];
        float s1 = 0.f, s2 = 0.f;
#pragma unroll
        for (int nt = 0; nt < 4; ++nt) {
          const int l = nt * 16 + lm;
          const float xh = bf2f(*(const unsigned short*)(
              sh + LDS_XN + l * 512 + (((unsigned)(2 * c)) ^ ((unsigned)((l & 7) << 4)))));
          const float v = xh * ms4.y + ms4.x + pacc[mt][nt][reg] + bp;
          y[nt] = v;
          s1 += v; s2 += v * v;
        }
        s1 += __shfl_xor(s1, 1); s2 += __shfl_xor(s2, 1);
        s1 += __shfl_xor(s1, 2); s2 += __shfl_xor(s2, 2);
        s1 += __shfl_xor(s1, 4); s2 += __shfl_xor(s2, 4);
        s1 += __shfl_xor(s1, 8); s2 += __shfl_xor(s2, 8);
        const float mean = s1 * (1.f / 64.f);
        const float var  = s2 * (1.f / 64.f) - mean * mean;
        const float rstd = rsqrtf(fmaxf(var, 0.f) + 1e-5f);
        float* orow = out + (size_t)b * 16384 + (size_t)c * 64;
#pragma unroll
        for (int nt = 0; nt < 4; ++nt) {
          const float v = y[nt];
          orow[nt * 16 + lm] = v + (v - mean) * rstd * pog4[nt] + pob4[nt];
        }
      }
    }
  }
}

extern "C" void kernel_launch(void* const* d_in, const int* in_sizes, int n_in,
                              void* d_out, int out_size, void* d_ws, size_t ws_size,
                              hipStream_t stream) {
  const float* X     = (const float*)d_in[0];
  const float* preg  = (const float*)d_in[1];
  const float* preb  = (const float*)d_in[2];
  const float* postg = (const float*)d_in[3];
  const float* postb = (const float*)d_in[4];
  const float* Wqkv  = (const float*)d_in[5];
  const float* bqkv  = (const float*)d_in[6];
  const float* Wproj = (const float*)d_in[7];
  const float* bproj = (const float*)d_in[8];
  const float* table = (const float*)d_in[9];

  unsigned short* wq = (unsigned short*)d_ws;                    // 768*256 bf16
  unsigned short* wp = (unsigned short*)((char*)d_ws + 393216);  // 256*256 bf16
  float* biasg       = (float*)((char*)d_ws + 524288);           // 8*64*64 f32
  float* rowsum      = (float*)((char*)d_ws + 655360);           // 768 f32

  prep_kernel<<<768, 256, 0, stream>>>(Wqkv, Wproj, table, wq, wp, biasg, rowsum);
  win_attn_kernel<<<2048, 512, 0, stream>>>(X, preg, preb, postg, postb,
                                            bqkv, bproj, wq, wp, biasg, rowsum,
                                            (float*)d_out);
}